// Round 18
// baseline (321.429 us; speedup 1.0000x reference)
//
#include <hip/hip_runtime.h>
#include <math.h>

// ---------------------------------------------------------------------------
// GCN diffusion forward on MI355X — round 18.
// vs R17: TWO-LEVEL binning for the CSR build.
//   bin: 64 fine buckets (LDS hist, per-block range reservation).
//   fill: XCD group x serially processes buckets [8x, 8x+8); each bucket's
//     cs region is ~300KB -> stays L2-resident while filled -> each dirty
//     line written back ONCE (was ~10x amplification with 8 coarse buckets).
// Rest = R15: 2-node sentinel-padded agg (32 gathers/wave), MFMA gemms,
// merged prep, pre-scaled bf16 activations.
// ---------------------------------------------------------------------------

typedef unsigned short ushortT;
typedef __attribute__((ext_vector_type(8))) short short8v;
typedef __attribute__((ext_vector_type(4))) float f32x4;

#define CSR_CAP 48
#define NBUCK 64

__device__ __forceinline__ ushortT f2bf(float f) {
    unsigned int u = __float_as_uint(f);
    u += 0x7FFFu + ((u >> 16) & 1u);     // round-to-nearest-even
    return (ushortT)(u >> 16);
}
__device__ __forceinline__ float bf2f(ushortT u) {
    return __uint_as_float(((unsigned int)u) << 16);
}

// ---- merged prep ----
// blocks [0,nblkN): zero cnt/flag (+bcnt in block 0)
// [nblkN, nblkN+csBlk): preset cs = sentinel N
// [.., +160): convw swizzle
// last: temb + zero gather-rows N of bufXT and xw1
__global__ __launch_bounds__(256) void prep_kernel(int* __restrict__ cnt,
                                                   int* __restrict__ flag,
                                                   int* __restrict__ bcnt,
                                                   int n, int nblkN, int csBlk,
                                                   int* __restrict__ cs,
                                                   const float* __restrict__ w0,
                                                   const float* __restrict__ w1,
                                                   const float* __restrict__ w2,
                                                   const float* __restrict__ w3,
                                                   ushortT* __restrict__ wdst,
                                                   const int* __restrict__ t,
                                                   const float* __restrict__ tw1,
                                                   const float* __restrict__ tb1,
                                                   const float* __restrict__ tw2,
                                                   const float* __restrict__ tb2,
                                                   float* __restrict__ temb,
                                                   ushortT* __restrict__ bufXT,
                                                   ushortT* __restrict__ xw1) {
    int bid = blockIdx.x;
    if (bid < nblkN) {
        int i = bid * 256 + threadIdx.x;
        if (i < n) { cnt[i] = 0; flag[i] = 0; }
        if (bid == 0 && threadIdx.x < NBUCK) bcnt[threadIdx.x] = 0;
        return;
    }
    if (bid < nblkN + csBlk) {
        size_t total = (size_t)n * CSR_CAP;
        size_t base = ((size_t)(bid - nblkN) * 256 + threadIdx.x) * 16;
        int4 sv = make_int4(n, n, n, n);
#pragma unroll
        for (int j = 0; j < 4; ++j) {
            size_t p = base + j * 4;
            if (p + 4 <= total) *(int4*)(cs + p) = sv;
            else for (size_t q = p; q < total; ++q) cs[q] = n;
        }
        return;
    }
    if (bid < nblkN + csBlk + 160) {
        int i = (bid - nblkN - csBlk) * 256 + threadIdx.x;
        if (i >= 40960) return;
        const float* src; int ST, M, base;
        if (i < 8192)       { src = w0; ST = 8; M = 128; base = 0; }
        else if (i < 16384) { src = w1; ST = 4; M = 64;  base = 8192; }
        else if (i < 24576) { src = w2; ST = 8; M = 128; base = 16384; }
        else                { src = w3; ST = 4; M = 64;  base = 24576; }
        int idx = i - base;
        int j = idx & 7;
        int lane = (idx >> 3) & 63;
        int rest = idx >> 9;
        int s = rest % ST;
        int kq = rest / ST;
        int k = kq * 32 + (lane >> 4) * 8 + j;
        int col = s * 16 + (lane & 15);
        wdst[i] = f2bf(src[(size_t)k * M + col]);
        return;
    }
    // temb block; threads 64-95/96-127 zero sentinel rows of bufXT / xw1
    __shared__ float emb[64], hid[64];
    int j = threadIdx.x;
    if (j >= 64 && j < 96)  ((unsigned int*)(bufXT + (size_t)n * 64))[j - 64] = 0u;
    if (j >= 96 && j < 128) ((unsigned int*)(xw1 + (size_t)n * 64))[j - 96] = 0u;
    if (j < 64) {
        float tf = (float)t[0];
        int h = j & 31;
        float freq = expf((float)h * -0.29710775393976190f);  // -ln(10000)/31
        float arg = tf * freq;
        emb[j] = (j < 32) ? sinf(arg) : cosf(arg);
    }
    __syncthreads();
    if (j < 64) {
        float a = tb1[j];
        for (int k = 0; k < 64; ++k) a = fmaf(emb[k], tw1[k * 64 + j], a);
        hid[j] = a / (1.0f + expf(-a));  // SiLU
    }
    __syncthreads();
    if (j < 64) {
        float o = tb2[j];
        for (int k = 0; k < 64; ++k) o = fmaf(hid[k], tw2[k * 64 + j], o);
        temb[j] = o;
    }
}

__global__ __launch_bounds__(256) void flags_kernel(const int* __restrict__ anm, int na,
                                                    const int* __restrict__ nrm, int nn,
                                                    int* __restrict__ flag) {
    int i = blockIdx.x * 256 + threadIdx.x;
    if (i < na) atomicMax(&flag[anm[i]], 1);
    if (i < nn) atomicMax(&flag[nrm[i]], 2);    // norm (2) overrides anm (1)
}

__global__ __launch_bounds__(256) void dinv_kernel(const int* __restrict__ cnt,
                                                   float* __restrict__ dinv, int n) {
    int i = blockIdx.x * 256 + threadIdx.x;
    if (i < n) dinv[i] = rsqrtf((float)cnt[i] + 1.0f);
}

// ---- Phase A: bin edges into 64 fine dst-buckets ----
__global__ __launch_bounds__(256) void bin_kernel(const int* __restrict__ ei,
                                                  int* __restrict__ bcnt,
                                                  int2* __restrict__ pairs,
                                                  int e, int bdiv, int capb) {
    __shared__ int hist[NBUCK];
    __shared__ int base[NBUCK];
    __shared__ int cur[NBUCK];
    int t = threadIdx.x;
    if (t < NBUCK) { hist[t] = 0; cur[t] = 0; }
    __syncthreads();
    int i0 = blockIdx.x * 2048 + t;
    int bk[8], sr[8], ds[8];
#pragma unroll
    for (int j = 0; j < 8; ++j) {
        int i = i0 + j * 256;
        if (i < e) {
            ds[j] = __builtin_nontemporal_load(ei + e + i);
            sr[j] = __builtin_nontemporal_load(ei + i);
            bk[j] = ds[j] / bdiv;
            atomicAdd(&hist[bk[j]], 1);
        } else bk[j] = -1;
    }
    __syncthreads();
    if (t < NBUCK) base[t] = atomicAdd(&bcnt[t], hist[t]);
    __syncthreads();
#pragma unroll
    for (int j = 0; j < 8; ++j) {
        if (bk[j] >= 0) {
            int p = atomicAdd(&cur[bk[j]], 1);
            pairs[(size_t)bk[j] * capb + base[bk[j]] + p] = make_int2(sr[j], ds[j]);
        }
    }
}

// ---- Phase B: XCD group x serially fills buckets [8x, 8x+8) ----
// Each bucket's cs region (~300KB) stays L2-resident while filled.
__global__ __launch_bounds__(256) void fill_bins_kernel(const int2* __restrict__ pairs,
                                                        const int* __restrict__ bcnt,
                                                        int* __restrict__ cnt,
                                                        int* __restrict__ cs, int capb) {
    int x = blockIdx.x & 7;
    int g = blockIdx.x >> 3;
    int G = gridDim.x >> 3;
    int tid0 = g * 256 + threadIdx.x;
    int stride = G * 256;
#pragma unroll 1
    for (int bb = 0; bb < 8; ++bb) {
        int b = x * 8 + bb;
        int nb = bcnt[b];
        const long long* pll = (const long long*)pairs + (size_t)b * capb;
        for (int i0 = tid0 * 4; i0 < nb; i0 += stride * 4) {
            long long v0 = 0, v1 = 0, v2 = 0, v3 = 0;
            int m = nb - i0;
            v0 = __builtin_nontemporal_load(pll + i0);
            if (m > 1) v1 = __builtin_nontemporal_load(pll + i0 + 1);
            if (m > 2) v2 = __builtin_nontemporal_load(pll + i0 + 2);
            if (m > 3) v3 = __builtin_nontemporal_load(pll + i0 + 3);
            int d0 = (int)(v0 >> 32), s0 = (int)v0;
            int d1 = (int)(v1 >> 32), s1 = (int)v1;
            int d2 = (int)(v2 >> 32), s2 = (int)v2;
            int d3 = (int)(v3 >> 32), s3 = (int)v3;
            int p0 = atomicAdd(&cnt[d0], 1);
            int p1 = (m > 1) ? atomicAdd(&cnt[d1], 1) : CSR_CAP;
            int p2 = (m > 2) ? atomicAdd(&cnt[d2], 1) : CSR_CAP;
            int p3 = (m > 3) ? atomicAdd(&cnt[d3], 1) : CSR_CAP;
            if (p0 < CSR_CAP) cs[(size_t)d0 * CSR_CAP + p0] = s0;
            if (p1 < CSR_CAP) cs[(size_t)d1 * CSR_CAP + p1] = s1;
            if (p2 < CSR_CAP) cs[(size_t)d2 * CSR_CAP + p2] = s2;
            if (p3 < CSR_CAP) cs[(size_t)d3 * CSR_CAP + p3] = s3;
        }
    }
}

// ---- x_t = (noise_x + temb + label_emb[flag]) * dinv[row]  -> bf16 ----
__global__ __launch_bounds__(256) void xt_kernel(const float* __restrict__ nx,
                                                 const float* __restrict__ temb,
                                                 const float* __restrict__ lemb,
                                                 const int* __restrict__ flag,
                                                 const float* __restrict__ dinv,
                                                 ushortT* __restrict__ xt, int n) {
    int t = blockIdx.x * 256 + threadIdx.x;
    int total = n * 16;
    if (t >= total) return;
    int row = t >> 4;
    int c4 = (t & 15) * 4;
    float4 v = *(const float4*)(nx + (size_t)row * 64 + c4);
    float4 tv = *(const float4*)(temb + c4);
    v.x += tv.x; v.y += tv.y; v.z += tv.z; v.w += tv.w;
    int f = flag[row];
    if (f) {
        const float* le = lemb + (f == 1 ? 64 : 0);  // 1->label_emb[1], 2->label_emb[0]
        float4 lv = *(const float4*)(le + c4);
        v.x += lv.x; v.y += lv.y; v.z += lv.z; v.w += lv.w;
    }
    float dv = dinv[row];
    v.x *= dv; v.y *= dv; v.z *= dv; v.w *= dv;
    unsigned int p0 = (unsigned int)f2bf(v.x) | ((unsigned int)f2bf(v.y) << 16);
    unsigned int p1 = (unsigned int)f2bf(v.z) | ((unsigned int)f2bf(v.w) << 16);
    *(uint2*)(xt + (size_t)row * 64 + c4) = make_uint2(p0, p1);
}

// ---------------------------------------------------------------------------
// MFMA GEMM: Y[n][M] = A[n][K] @ W (bf16 in, f32 acc). Wave = 16 rows x M.
// ---------------------------------------------------------------------------
template <int KQT, int ST, bool BIAS_SILU, bool OUT_BF16, bool CAT, bool SCALE>
__global__ __launch_bounds__(256) void mfma_gemm_kernel(const ushortT* __restrict__ A1,
                                                        const ushortT* __restrict__ A2,
                                                        const ushortT* __restrict__ Wswz,
                                                        const float* __restrict__ bias,
                                                        const float* __restrict__ dinvp,
                                                        void* __restrict__ Yv, int n) {
    constexpr int M = ST * 16;
    constexpr int KA = (CAT ? (KQT / 2) : KQT) * 32;   // per-source row stride
    const int lane = threadIdx.x & 63;
    const int wid = threadIdx.x >> 6;
    const int row0 = blockIdx.x * 64 + wid * 16;
    const int arow = row0 + (lane & 15);
    const int kb = (lane >> 4) * 8;

    f32x4 acc[ST];
#pragma unroll
    for (int s = 0; s < ST; ++s) acc[s] = (f32x4){0.f, 0.f, 0.f, 0.f};

#pragma unroll
    for (int kq = 0; kq < KQT; ++kq) {
        const ushortT* Asrc = (CAT && kq >= KQT / 2) ? A2 : A1;
        const int kloc = (CAT && kq >= KQT / 2) ? (kq - KQT / 2) * 32 : kq * 32;
        short8v a = *(const short8v*)(Asrc + (size_t)arow * KA + kloc + kb);
        const ushortT* wp = Wswz + ((size_t)(kq * ST) * 64 + lane) * 8;
#pragma unroll
        for (int s = 0; s < ST; ++s) {
            short8v b = *(const short8v*)(wp + (size_t)s * 64 * 8);
            acc[s] = __builtin_amdgcn_mfma_f32_16x16x32_bf16(a, b, acc[s], 0, 0, 0);
        }
    }

    const int dcol = lane & 15;
    const int drow0 = row0 + (lane >> 4) * 4;
    float sc[4];
    if (SCALE) {
#pragma unroll
        for (int r = 0; r < 4; ++r) sc[r] = (drow0 + r < n) ? dinvp[drow0 + r] : 0.f;
    }
#pragma unroll
    for (int s = 0; s < ST; ++s) {
        float bv = BIAS_SILU ? bias[s * 16 + dcol] : 0.f;
#pragma unroll
        for (int r = 0; r < 4; ++r) {
            int row = drow0 + r;
            if (row >= n) continue;
            float v = acc[s][r];
            if (BIAS_SILU) { v += bv; v = v / (1.0f + expf(-v)); }
            if (SCALE) v *= sc[r];
            if (OUT_BF16) ((ushortT*)Yv)[(size_t)row * M + s * 16 + dcol] = f2bf(v);
            else          ((float*)Yv)[(size_t)row * M + s * 16 + dcol] = v;
        }
    }
}

// ---------------------------------------------------------------------------
// Sentinel-padded agg (R15): TWO nodes per wave, 32 unconditional gathers in
// flight. Overflow loop for deg>16 (~3%).
// out[dst] = dinv[dst]*(sum_src xs[src] + xs[dst]) (+bias,silu,post-scale).
// ---------------------------------------------------------------------------
template <bool BIAS_SILU, bool OUT_BF16, bool POST_SCALE>
__global__ __launch_bounds__(256) void agg64_kernel(const ushortT* __restrict__ xw,
                                                    const int* __restrict__ cnt,
                                                    const int* __restrict__ cs,
                                                    const float* __restrict__ dinv,
                                                    const float* __restrict__ bias,
                                                    void* __restrict__ yv, int n) {
    int pair = (int)(((size_t)blockIdx.x * 256 + threadIdx.x) >> 6);
    int lane = threadIdx.x & 63;
    int nA = pair * 2;
    int nB = nA + 1;
    if (nA >= n) return;
    bool hasB = (nB < n);
    const int* rA = cs + (size_t)nA * CSR_CAP;
    const int* rB = cs + (size_t)nB * CSR_CAP;

    int ia[16], ib[16];
#pragma unroll
    for (int j = 0; j < 16; ++j) ia[j] = rA[j];
#pragma unroll
    for (int j = 0; j < 16; ++j) ib[j] = hasB ? rB[j] : n;

    float va[16], vb[16];
#pragma unroll
    for (int j = 0; j < 16; ++j) va[j] = bf2f(xw[(size_t)ia[j] * 64 + lane]);
#pragma unroll
    for (int j = 0; j < 16; ++j) vb[j] = bf2f(xw[(size_t)ib[j] * 64 + lane]);

    float a0 = (va[0] + va[1]) + (va[2] + va[3]);
    float a1 = (va[4] + va[5]) + (va[6] + va[7]);
    float a2 = (va[8] + va[9]) + (va[10] + va[11]);
    float a3 = (va[12] + va[13]) + (va[14] + va[15]);
    float b0 = (vb[0] + vb[1]) + (vb[2] + vb[3]);
    float b1 = (vb[4] + vb[5]) + (vb[6] + vb[7]);
    float b2 = (vb[8] + vb[9]) + (vb[10] + vb[11]);
    float b3 = (vb[12] + vb[13]) + (vb[14] + vb[15]);

    // overflow (deg > 16), rare
    int cA = cnt[nA]; if (cA > CSR_CAP) cA = CSR_CAP;
    int cB = hasB ? cnt[nB] : 0; if (cB > CSR_CAP) cB = CSR_CAP;
    for (int j = 16; j < cA; ++j) a0 += bf2f(xw[(size_t)rA[j] * 64 + lane]);
    for (int j = 16; j < cB; ++j) b0 += bf2f(xw[(size_t)rB[j] * 64 + lane]);

    // epilogue A
    {
        float di = dinv[nA];
        float acc = (a0 + a1) + (a2 + a3);
        acc += bf2f(xw[(size_t)nA * 64 + lane]);   // self term (pre-scaled)
        acc *= di;
        if (BIAS_SILU) {
            acc += bias[lane];
            acc = acc / (1.0f + expf(-acc));
        }
        if (POST_SCALE) acc *= di;
        if (OUT_BF16) ((ushortT*)yv)[(size_t)nA * 64 + lane] = f2bf(acc);
        else          ((float*)yv)[(size_t)nA * 64 + lane] = acc;
    }
    // epilogue B
    if (hasB) {
        float di = dinv[nB];
        float acc = (b0 + b1) + (b2 + b3);
        acc += bf2f(xw[(size_t)nB * 64 + lane]);
        acc *= di;
        if (BIAS_SILU) {
            acc += bias[lane];
            acc = acc / (1.0f + expf(-acc));
        }
        if (POST_SCALE) acc *= di;
        if (OUT_BF16) ((ushortT*)yv)[(size_t)nB * 64 + lane] = f2bf(acc);
        else          ((float*)yv)[(size_t)nB * 64 + lane] = acc;
    }
}

extern "C" void kernel_launch(void* const* d_in, const int* in_sizes, int n_in,
                              void* d_out, int out_size, void* d_ws, size_t ws_size,
                              hipStream_t stream) {
    const float* noise_x = (const float*)d_in[0];
    const int*   edge    = (const int*)d_in[1];
    const int*   tptr    = (const int*)d_in[2];
    const int*   anm     = (const int*)d_in[3];
    const int*   nrm     = (const int*)d_in[4];
    const float* tw1     = (const float*)d_in[5];
    const float* tb1     = (const float*)d_in[6];
    const float* tw2     = (const float*)d_in[7];
    const float* tb2     = (const float*)d_in[8];
    const float* lemb    = (const float*)d_in[9];
    const float* w0      = (const float*)d_in[10];
    const float* b0      = (const float*)d_in[11];
    const float* w1      = (const float*)d_in[12];
    const float* b1      = (const float*)d_in[13];
    const float* w2      = (const float*)d_in[14];
    const float* b2      = (const float*)d_in[15];
    const float* w3      = (const float*)d_in[16];
    const float* b3      = (const float*)d_in[17];

    const int N = in_sizes[0] / 64;
    const int E = in_sizes[1] / 2;
    const int na = in_sizes[3];
    const int nn = in_sizes[4];
    float* out = (float*)d_out;

    // workspace carve-out (256B aligned)
    char* ws = (char*)d_ws;
    size_t o = 0;
    auto carve = [&](size_t bytes) -> char* {
        char* p = ws + o;
        o += (bytes + 255) & ~(size_t)255;
        return p;
    };
    const int capb = E / NBUCK + 4096;
    int*     cnt      = (int*)carve((size_t)N * 4);
    int*     flag     = (int*)carve((size_t)N * 4);
    int*     bcnt     = (int*)carve(NBUCK * 4);
    int2*    pairs    = (int2*)carve((size_t)capb * NBUCK * 8);
    int*     cs       = (int*)carve((size_t)N * CSR_CAP * 4);
    float*   dinv     = (float*)carve((size_t)N * 4);
    float*   temb     = (float*)carve(256);
    ushortT* wswz     = (ushortT*)carve(40960 * 2);
    ushortT* bufXT    = (ushortT*)carve((size_t)(N + 1) * 64 * 2); // x_t*dinv -> h1s (+zero row N)
    ushortT* aggX     = (ushortT*)carve((size_t)N * 64 * 2);       // agg0 out
    ushortT* h0       = (ushortT*)carve((size_t)N * 128 * 2);      // G0 out (live to end)
    ushortT* xw1      = (ushortT*)carve((size_t)(N + 1) * 64 * 2); // G1 out -> z3 (+zero row N)
    ushortT* aggH1    = (ushortT*)carve((size_t)N * 64 * 2);       // agg2 out
    ushortT* h2       = (ushortT*)carve((size_t)N * 128 * 2);      // G2 out
    ushortT* h1s      = bufXT;                                      // reuse (row N stays zero)
    ushortT* z3       = xw1;                                        // reuse (row N stays zero)

    const int nblkN = (N + 255) / 256;
    const int nmax = na > nn ? na : nn;
    const int aggBlk = (N + 7) / 8;          // 4 waves x 2 nodes per block
    const int gblk = (N + 63) / 64;          // 64 rows per mfma-gemm block
    const int bdiv = (N + NBUCK - 1) / NBUCK; // fine-bucket size
    const int binBlk = (E + 2047) / 2048;
    const int csBlk = (int)(((size_t)N * CSR_CAP + 4095) / 4096);  // 16 ints/thread

    prep_kernel<<<nblkN + csBlk + 161, 256, 0, stream>>>(cnt, flag, bcnt, N, nblkN, csBlk, cs,
                                                         w0, w1, w2, w3, wswz,
                                                         tptr, tw1, tb1, tw2, tb2, temb,
                                                         bufXT, xw1);
    flags_kernel<<<(nmax + 255) / 256, 256, 0, stream>>>(anm, na, nrm, nn, flag);
    bin_kernel<<<binBlk, 256, 0, stream>>>(edge, bcnt, pairs, E, bdiv, capb);
    fill_bins_kernel<<<8 * 64, 256, 0, stream>>>(pairs, bcnt, cnt, cs, capb);
    dinv_kernel<<<nblkN, 256, 0, stream>>>(cnt, dinv, N);
    xt_kernel<<<((size_t)N * 16 + 255) / 256, 256, 0, stream>>>(noise_x, temb, lemb, flag, dinv, bufXT, N);

    // conv0: aggX = agg(x_t) [bf16]; h0 = silu(aggX @ w0 + b0) [bf16]
    agg64_kernel<false, true, false><<<aggBlk, 256, 0, stream>>>(bufXT, cnt, cs, dinv, nullptr, aggX, N);
    mfma_gemm_kernel<2, 8, true, true, false, false><<<gblk, 256, 0, stream>>>(aggX, nullptr, wswz, b0, nullptr, h0, N);
    // conv1: xw1 = (h0 @ w1)*dinv [bf16]; h1s = silu(agg+b1)*dinv [bf16]
    mfma_gemm_kernel<4, 4, false, true, false, true><<<gblk, 256, 0, stream>>>(h0, nullptr, wswz + 8192, nullptr, dinv, xw1, N);
    agg64_kernel<true, true, true><<<aggBlk, 256, 0, stream>>>(xw1, cnt, cs, dinv, b1, h1s, N);
    // conv2: aggH1 = agg(h1) [bf16]; h2 = silu(aggH1 @ w2 + b2) [bf16]
    agg64_kernel<false, true, false><<<aggBlk, 256, 0, stream>>>(h1s, cnt, cs, dinv, nullptr, aggH1, N);
    mfma_gemm_kernel<2, 8, true, true, false, false><<<gblk, 256, 0, stream>>>(aggH1, nullptr, wswz + 16384, b2, nullptr, h2, N);
    // conv3: z3 = (h2 @ w3a + h0 @ w3b)*dinv [bf16]; out = silu(agg + b3) [f32]
    mfma_gemm_kernel<8, 4, false, true, true, true><<<gblk, 256, 0, stream>>>(h2, h0, wswz + 24576, nullptr, dinv, z3, N);
    agg64_kernel<true, false, false><<<aggBlk, 256, 0, stream>>>(z3, cnt, cs, dinv, b3, out, N);
}

// Round 19
// 255.145 us; speedup vs baseline: 1.2598x; 1.2598x over previous
//
#include <hip/hip_runtime.h>
#include <math.h>

// ---------------------------------------------------------------------------
// GCN diffusion forward on MI355X — round 19.
// = R15 (best, 292us) +
//  * fill_csr: NONTEMPORAL scatter stores for cs (bypass L2 line churn).
//  * agg64: node index scalarized via readfirstlane -> cs index loads go to
//    the scalar pipe (s_load), freeing VGPRs and VMEM queue slots.
// ---------------------------------------------------------------------------

typedef unsigned short ushortT;
typedef __attribute__((ext_vector_type(8))) short short8v;
typedef __attribute__((ext_vector_type(4))) float f32x4;

#define CSR_CAP 48

__device__ __forceinline__ ushortT f2bf(float f) {
    unsigned int u = __float_as_uint(f);
    u += 0x7FFFu + ((u >> 16) & 1u);     // round-to-nearest-even
    return (ushortT)(u >> 16);
}
__device__ __forceinline__ float bf2f(ushortT u) {
    return __uint_as_float(((unsigned int)u) << 16);
}

// ---- merged prep ----
// blocks [0,nblkN): zero cnt/flag
// [nblkN, nblkN+csBlk): preset cs = sentinel N
// [.., +160): convw swizzle
// last: temb + zero gather-rows N of bufXT and xw1
__global__ __launch_bounds__(256) void prep_kernel(int* __restrict__ cnt,
                                                   int* __restrict__ flag,
                                                   int n, int nblkN, int csBlk,
                                                   int* __restrict__ cs,
                                                   const float* __restrict__ w0,
                                                   const float* __restrict__ w1,
                                                   const float* __restrict__ w2,
                                                   const float* __restrict__ w3,
                                                   ushortT* __restrict__ wdst,
                                                   const int* __restrict__ t,
                                                   const float* __restrict__ tw1,
                                                   const float* __restrict__ tb1,
                                                   const float* __restrict__ tw2,
                                                   const float* __restrict__ tb2,
                                                   float* __restrict__ temb,
                                                   ushortT* __restrict__ bufXT,
                                                   ushortT* __restrict__ xw1) {
    int bid = blockIdx.x;
    if (bid < nblkN) {
        int i = bid * 256 + threadIdx.x;
        if (i < n) { cnt[i] = 0; flag[i] = 0; }
        return;
    }
    if (bid < nblkN + csBlk) {
        size_t total = (size_t)n * CSR_CAP;
        size_t base = ((size_t)(bid - nblkN) * 256 + threadIdx.x) * 16;
        int4 sv = make_int4(n, n, n, n);
#pragma unroll
        for (int j = 0; j < 4; ++j) {
            size_t p = base + j * 4;
            if (p + 4 <= total) *(int4*)(cs + p) = sv;
            else for (size_t q = p; q < total; ++q) cs[q] = n;
        }
        return;
    }
    if (bid < nblkN + csBlk + 160) {
        int i = (bid - nblkN - csBlk) * 256 + threadIdx.x;
        if (i >= 40960) return;
        const float* src; int ST, M, base;
        if (i < 8192)       { src = w0; ST = 8; M = 128; base = 0; }
        else if (i < 16384) { src = w1; ST = 4; M = 64;  base = 8192; }
        else if (i < 24576) { src = w2; ST = 8; M = 128; base = 16384; }
        else                { src = w3; ST = 4; M = 64;  base = 24576; }
        int idx = i - base;
        int j = idx & 7;
        int lane = (idx >> 3) & 63;
        int rest = idx >> 9;
        int s = rest % ST;
        int kq = rest / ST;
        int k = kq * 32 + (lane >> 4) * 8 + j;
        int col = s * 16 + (lane & 15);
        wdst[i] = f2bf(src[(size_t)k * M + col]);
        return;
    }
    // temb block; threads 64-95/96-127 zero sentinel rows of bufXT / xw1
    __shared__ float emb[64], hid[64];
    int j = threadIdx.x;
    if (j >= 64 && j < 96)  ((unsigned int*)(bufXT + (size_t)n * 64))[j - 64] = 0u;
    if (j >= 96 && j < 128) ((unsigned int*)(xw1 + (size_t)n * 64))[j - 96] = 0u;
    if (j < 64) {
        float tf = (float)t[0];
        int h = j & 31;
        float freq = expf((float)h * -0.29710775393976190f);  // -ln(10000)/31
        float arg = tf * freq;
        emb[j] = (j < 32) ? sinf(arg) : cosf(arg);
    }
    __syncthreads();
    if (j < 64) {
        float a = tb1[j];
        for (int k = 0; k < 64; ++k) a = fmaf(emb[k], tw1[k * 64 + j], a);
        hid[j] = a / (1.0f + expf(-a));  // SiLU
    }
    __syncthreads();
    if (j < 64) {
        float o = tb2[j];
        for (int k = 0; k < 64; ++k) o = fmaf(hid[k], tw2[k * 64 + j], o);
        temb[j] = o;
    }
}

__global__ __launch_bounds__(256) void flags_kernel(const int* __restrict__ anm, int na,
                                                    const int* __restrict__ nrm, int nn,
                                                    int* __restrict__ flag) {
    int i = blockIdx.x * 256 + threadIdx.x;
    if (i < na) atomicMax(&flag[anm[i]], 1);
    if (i < nn) atomicMax(&flag[nrm[i]], 2);    // norm (2) overrides anm (1)
}

__global__ __launch_bounds__(256) void dinv_kernel(const int* __restrict__ cnt,
                                                   float* __restrict__ dinv, int n) {
    int i = blockIdx.x * 256 + threadIdx.x;
    if (i < n) dinv[i] = rsqrtf((float)cnt[i] + 1.0f);
}

// Padded-CSR fill, XCD-partitioned: block handles edge chunk (blockIdx>>3);
// only dst bucket == (blockIdx&7) written. NT edge reads; NT scatter stores.
__global__ __launch_bounds__(256) void fill_csr_kernel(const int* __restrict__ ei,
                                                       int* __restrict__ cnt,
                                                       int* __restrict__ cs, int e, int bdiv) {
    int xcd = blockIdx.x & 7;
    int i = (blockIdx.x >> 3) * 256 + threadIdx.x;
    if (i >= e) return;
    int dst = __builtin_nontemporal_load(ei + e + i);
    if (dst / bdiv != xcd) return;
    int src = __builtin_nontemporal_load(ei + i);
    int p = atomicAdd(&cnt[dst], 1);
    if (p < CSR_CAP) __builtin_nontemporal_store(src, cs + (size_t)dst * CSR_CAP + p);
}

// ---- x_t = (noise_x + temb + label_emb[flag]) * dinv[row]  -> bf16 ----
__global__ __launch_bounds__(256) void xt_kernel(const float* __restrict__ nx,
                                                 const float* __restrict__ temb,
                                                 const float* __restrict__ lemb,
                                                 const int* __restrict__ flag,
                                                 const float* __restrict__ dinv,
                                                 ushortT* __restrict__ xt, int n) {
    int t = blockIdx.x * 256 + threadIdx.x;
    int total = n * 16;
    if (t >= total) return;
    int row = t >> 4;
    int c4 = (t & 15) * 4;
    float4 v = *(const float4*)(nx + (size_t)row * 64 + c4);
    float4 tv = *(const float4*)(temb + c4);
    v.x += tv.x; v.y += tv.y; v.z += tv.z; v.w += tv.w;
    int f = flag[row];
    if (f) {
        const float* le = lemb + (f == 1 ? 64 : 0);  // 1->label_emb[1], 2->label_emb[0]
        float4 lv = *(const float4*)(le + c4);
        v.x += lv.x; v.y += lv.y; v.z += lv.z; v.w += lv.w;
    }
    float dv = dinv[row];
    v.x *= dv; v.y *= dv; v.z *= dv; v.w *= dv;
    unsigned int p0 = (unsigned int)f2bf(v.x) | ((unsigned int)f2bf(v.y) << 16);
    unsigned int p1 = (unsigned int)f2bf(v.z) | ((unsigned int)f2bf(v.w) << 16);
    *(uint2*)(xt + (size_t)row * 64 + c4) = make_uint2(p0, p1);
}

// ---------------------------------------------------------------------------
// MFMA GEMM: Y[n][M] = A[n][K] @ W (bf16 in, f32 acc). Wave = 16 rows x M.
// ---------------------------------------------------------------------------
template <int KQT, int ST, bool BIAS_SILU, bool OUT_BF16, bool CAT, bool SCALE>
__global__ __launch_bounds__(256) void mfma_gemm_kernel(const ushortT* __restrict__ A1,
                                                        const ushortT* __restrict__ A2,
                                                        const ushortT* __restrict__ Wswz,
                                                        const float* __restrict__ bias,
                                                        const float* __restrict__ dinvp,
                                                        void* __restrict__ Yv, int n) {
    constexpr int M = ST * 16;
    constexpr int KA = (CAT ? (KQT / 2) : KQT) * 32;   // per-source row stride
    const int lane = threadIdx.x & 63;
    const int wid = threadIdx.x >> 6;
    const int row0 = blockIdx.x * 64 + wid * 16;
    const int arow = row0 + (lane & 15);
    const int kb = (lane >> 4) * 8;

    f32x4 acc[ST];
#pragma unroll
    for (int s = 0; s < ST; ++s) acc[s] = (f32x4){0.f, 0.f, 0.f, 0.f};

#pragma unroll
    for (int kq = 0; kq < KQT; ++kq) {
        const ushortT* Asrc = (CAT && kq >= KQT / 2) ? A2 : A1;
        const int kloc = (CAT && kq >= KQT / 2) ? (kq - KQT / 2) * 32 : kq * 32;
        short8v a = *(const short8v*)(Asrc + (size_t)arow * KA + kloc + kb);
        const ushortT* wp = Wswz + ((size_t)(kq * ST) * 64 + lane) * 8;
#pragma unroll
        for (int s = 0; s < ST; ++s) {
            short8v b = *(const short8v*)(wp + (size_t)s * 64 * 8);
            acc[s] = __builtin_amdgcn_mfma_f32_16x16x32_bf16(a, b, acc[s], 0, 0, 0);
        }
    }

    const int dcol = lane & 15;
    const int drow0 = row0 + (lane >> 4) * 4;
    float sc[4];
    if (SCALE) {
#pragma unroll
        for (int r = 0; r < 4; ++r) sc[r] = (drow0 + r < n) ? dinvp[drow0 + r] : 0.f;
    }
#pragma unroll
    for (int s = 0; s < ST; ++s) {
        float bv = BIAS_SILU ? bias[s * 16 + dcol] : 0.f;
#pragma unroll
        for (int r = 0; r < 4; ++r) {
            int row = drow0 + r;
            if (row >= n) continue;
            float v = acc[s][r];
            if (BIAS_SILU) { v += bv; v = v / (1.0f + expf(-v)); }
            if (SCALE) v *= sc[r];
            if (OUT_BF16) ((ushortT*)Yv)[(size_t)row * M + s * 16 + dcol] = f2bf(v);
            else          ((float*)Yv)[(size_t)row * M + s * 16 + dcol] = v;
        }
    }
}

// ---------------------------------------------------------------------------
// Sentinel-padded agg (R15): TWO nodes per wave, 32 unconditional gathers in
// flight. Node indices scalarized (readfirstlane) -> cs index loads use the
// scalar pipe/cache, freeing VGPRs + VMEM queue. Overflow loop for deg>16.
// out[dst] = dinv[dst]*(sum_src xs[src] + xs[dst]) (+bias,silu,post-scale).
// ---------------------------------------------------------------------------
template <bool BIAS_SILU, bool OUT_BF16, bool POST_SCALE>
__global__ __launch_bounds__(256) void agg64_kernel(const ushortT* __restrict__ xw,
                                                    const int* __restrict__ cnt,
                                                    const int* __restrict__ cs,
                                                    const float* __restrict__ dinv,
                                                    const float* __restrict__ bias,
                                                    void* __restrict__ yv, int n) {
    int pair = (int)(((size_t)blockIdx.x * 256 + threadIdx.x) >> 6);
    int lane = threadIdx.x & 63;
    int nA = pair * 2;
    if (nA >= n) return;
    nA = __builtin_amdgcn_readfirstlane(nA);   // wave-uniform: force scalar
    int nB = nA + 1;
    bool hasB = (nB < n);
    const int* rA = cs + (size_t)nA * CSR_CAP;
    const int* rB = cs + (size_t)nB * CSR_CAP;

    int ia[16], ib[16];
#pragma unroll
    for (int j = 0; j < 16; ++j) ia[j] = rA[j];
#pragma unroll
    for (int j = 0; j < 16; ++j) ib[j] = hasB ? rB[j] : n;

    float va[16], vb[16];
#pragma unroll
    for (int j = 0; j < 16; ++j) va[j] = bf2f(xw[(size_t)ia[j] * 64 + lane]);
#pragma unroll
    for (int j = 0; j < 16; ++j) vb[j] = bf2f(xw[(size_t)ib[j] * 64 + lane]);

    float a0 = (va[0] + va[1]) + (va[2] + va[3]);
    float a1 = (va[4] + va[5]) + (va[6] + va[7]);
    float a2 = (va[8] + va[9]) + (va[10] + va[11]);
    float a3 = (va[12] + va[13]) + (va[14] + va[15]);
    float b0 = (vb[0] + vb[1]) + (vb[2] + vb[3]);
    float b1 = (vb[4] + vb[5]) + (vb[6] + vb[7]);
    float b2 = (vb[8] + vb[9]) + (vb[10] + vb[11]);
    float b3 = (vb[12] + vb[13]) + (vb[14] + vb[15]);

    // overflow (deg > 16), rare
    int cA = cnt[nA]; if (cA > CSR_CAP) cA = CSR_CAP;
    int cB = hasB ? cnt[nB] : 0; if (cB > CSR_CAP) cB = CSR_CAP;
    for (int j = 16; j < cA; ++j) a0 += bf2f(xw[(size_t)rA[j] * 64 + lane]);
    for (int j = 16; j < cB; ++j) b0 += bf2f(xw[(size_t)rB[j] * 64 + lane]);

    // epilogue A
    {
        float di = dinv[nA];
        float acc = (a0 + a1) + (a2 + a3);
        acc += bf2f(xw[(size_t)nA * 64 + lane]);   // self term (pre-scaled)
        acc *= di;
        if (BIAS_SILU) {
            acc += bias[lane];
            acc = acc / (1.0f + expf(-acc));
        }
        if (POST_SCALE) acc *= di;
        if (OUT_BF16) ((ushortT*)yv)[(size_t)nA * 64 + lane] = f2bf(acc);
        else          ((float*)yv)[(size_t)nA * 64 + lane] = acc;
    }
    // epilogue B
    if (hasB) {
        float di = dinv[nB];
        float acc = (b0 + b1) + (b2 + b3);
        acc += bf2f(xw[(size_t)nB * 64 + lane]);
        acc *= di;
        if (BIAS_SILU) {
            acc += bias[lane];
            acc = acc / (1.0f + expf(-acc));
        }
        if (POST_SCALE) acc *= di;
        if (OUT_BF16) ((ushortT*)yv)[(size_t)nB * 64 + lane] = f2bf(acc);
        else          ((float*)yv)[(size_t)nB * 64 + lane] = acc;
    }
}

extern "C" void kernel_launch(void* const* d_in, const int* in_sizes, int n_in,
                              void* d_out, int out_size, void* d_ws, size_t ws_size,
                              hipStream_t stream) {
    const float* noise_x = (const float*)d_in[0];
    const int*   edge    = (const int*)d_in[1];
    const int*   tptr    = (const int*)d_in[2];
    const int*   anm     = (const int*)d_in[3];
    const int*   nrm     = (const int*)d_in[4];
    const float* tw1     = (const float*)d_in[5];
    const float* tb1     = (const float*)d_in[6];
    const float* tw2     = (const float*)d_in[7];
    const float* tb2     = (const float*)d_in[8];
    const float* lemb    = (const float*)d_in[9];
    const float* w0      = (const float*)d_in[10];
    const float* b0      = (const float*)d_in[11];
    const float* w1      = (const float*)d_in[12];
    const float* b1      = (const float*)d_in[13];
    const float* w2      = (const float*)d_in[14];
    const float* b2      = (const float*)d_in[15];
    const float* w3      = (const float*)d_in[16];
    const float* b3      = (const float*)d_in[17];

    const int N = in_sizes[0] / 64;
    const int E = in_sizes[1] / 2;
    const int na = in_sizes[3];
    const int nn = in_sizes[4];
    float* out = (float*)d_out;

    // workspace carve-out (256B aligned)
    char* ws = (char*)d_ws;
    size_t o = 0;
    auto carve = [&](size_t bytes) -> char* {
        char* p = ws + o;
        o += (bytes + 255) & ~(size_t)255;
        return p;
    };
    int*     cnt      = (int*)carve((size_t)N * 4);
    int*     flag     = (int*)carve((size_t)N * 4);
    int*     cs       = (int*)carve((size_t)N * CSR_CAP * 4);
    float*   dinv     = (float*)carve((size_t)N * 4);
    float*   temb     = (float*)carve(256);
    ushortT* wswz     = (ushortT*)carve(40960 * 2);
    ushortT* bufXT    = (ushortT*)carve((size_t)(N + 1) * 64 * 2); // x_t*dinv -> h1s (+zero row N)
    ushortT* aggX     = (ushortT*)carve((size_t)N * 64 * 2);       // agg0 out
    ushortT* h0       = (ushortT*)carve((size_t)N * 128 * 2);      // G0 out (live to end)
    ushortT* xw1      = (ushortT*)carve((size_t)(N + 1) * 64 * 2); // G1 out -> z3 (+zero row N)
    ushortT* aggH1    = (ushortT*)carve((size_t)N * 64 * 2);       // agg2 out
    ushortT* h2       = (ushortT*)carve((size_t)N * 128 * 2);      // G2 out
    ushortT* h1s      = bufXT;                                      // reuse (row N stays zero)
    ushortT* z3       = xw1;                                        // reuse (row N stays zero)

    const int nblkN = (N + 255) / 256;
    const int nblkE = (E + 255) / 256;
    const int nmax = na > nn ? na : nn;
    const int aggBlk = (N + 7) / 8;          // 4 waves x 2 nodes per block
    const int gblk = (N + 63) / 64;          // 64 rows per mfma-gemm block
    const int bdiv = (N + 7) / 8;            // dst bucket size for XCD partition
    const int csBlk = (int)(((size_t)N * CSR_CAP + 4095) / 4096);  // 16 ints/thread

    prep_kernel<<<nblkN + csBlk + 161, 256, 0, stream>>>(cnt, flag, N, nblkN, csBlk, cs,
                                                         w0, w1, w2, w3, wswz,
                                                         tptr, tw1, tb1, tw2, tb2, temb,
                                                         bufXT, xw1);
    flags_kernel<<<(nmax + 255) / 256, 256, 0, stream>>>(anm, na, nrm, nn, flag);
    fill_csr_kernel<<<8 * nblkE, 256, 0, stream>>>(edge, cnt, cs, E, bdiv);
    dinv_kernel<<<nblkN, 256, 0, stream>>>(cnt, dinv, N);
    xt_kernel<<<((size_t)N * 16 + 255) / 256, 256, 0, stream>>>(noise_x, temb, lemb, flag, dinv, bufXT, N);

    // conv0: aggX = agg(x_t) [bf16]; h0 = silu(aggX @ w0 + b0) [bf16]
    agg64_kernel<false, true, false><<<aggBlk, 256, 0, stream>>>(bufXT, cnt, cs, dinv, nullptr, aggX, N);
    mfma_gemm_kernel<2, 8, true, true, false, false><<<gblk, 256, 0, stream>>>(aggX, nullptr, wswz, b0, nullptr, h0, N);
    // conv1: xw1 = (h0 @ w1)*dinv [bf16]; h1s = silu(agg+b1)*dinv [bf16]
    mfma_gemm_kernel<4, 4, false, true, false, true><<<gblk, 256, 0, stream>>>(h0, nullptr, wswz + 8192, nullptr, dinv, xw1, N);
    agg64_kernel<true, true, true><<<aggBlk, 256, 0, stream>>>(xw1, cnt, cs, dinv, b1, h1s, N);
    // conv2: aggH1 = agg(h1) [bf16]; h2 = silu(aggH1 @ w2 + b2) [bf16]
    agg64_kernel<false, true, false><<<aggBlk, 256, 0, stream>>>(h1s, cnt, cs, dinv, nullptr, aggH1, N);
    mfma_gemm_kernel<2, 8, true, true, false, false><<<gblk, 256, 0, stream>>>(aggH1, nullptr, wswz + 16384, b2, nullptr, h2, N);
    // conv3: z3 = (h2 @ w3a + h0 @ w3b)*dinv [bf16]; out = silu(agg + b3) [f32]
    mfma_gemm_kernel<8, 4, false, true, true, true><<<gblk, 256, 0, stream>>>(h2, h0, wswz + 24576, nullptr, dinv, z3, N);
    agg64_kernel<true, false, false><<<aggBlk, 256, 0, stream>>>(z3, cnt, cs, dinv, b3, out, N);
}

// Round 20
// 246.741 us; speedup vs baseline: 1.3027x; 1.0341x over previous
//
#include <hip/hip_runtime.h>
#include <math.h>

// ---------------------------------------------------------------------------
// GCN diffusion forward on MI355X — round 20.
// = R19 (best, 255us) with fill_csr fixed per counters:
//  * edge reads CACHED (was NT): the 4MB dst stream is re-read by all 8 XCD
//    groups -> L3-resident after pass 1; cuts the serial filter chain's load
//    latency ~4x (FETCH 31MB was 8x HBM re-fetch).
//  * cs store back to regular (NT store raised WRITE 40->51MB, no dur gain).
// ---------------------------------------------------------------------------

typedef unsigned short ushortT;
typedef __attribute__((ext_vector_type(8))) short short8v;
typedef __attribute__((ext_vector_type(4))) float f32x4;

#define CSR_CAP 48

__device__ __forceinline__ ushortT f2bf(float f) {
    unsigned int u = __float_as_uint(f);
    u += 0x7FFFu + ((u >> 16) & 1u);     // round-to-nearest-even
    return (ushortT)(u >> 16);
}
__device__ __forceinline__ float bf2f(ushortT u) {
    return __uint_as_float(((unsigned int)u) << 16);
}

// ---- merged prep ----
// blocks [0,nblkN): zero cnt/flag
// [nblkN, nblkN+csBlk): preset cs = sentinel N
// [.., +160): convw swizzle
// last: temb + zero gather-rows N of bufXT and xw1
__global__ __launch_bounds__(256) void prep_kernel(int* __restrict__ cnt,
                                                   int* __restrict__ flag,
                                                   int n, int nblkN, int csBlk,
                                                   int* __restrict__ cs,
                                                   const float* __restrict__ w0,
                                                   const float* __restrict__ w1,
                                                   const float* __restrict__ w2,
                                                   const float* __restrict__ w3,
                                                   ushortT* __restrict__ wdst,
                                                   const int* __restrict__ t,
                                                   const float* __restrict__ tw1,
                                                   const float* __restrict__ tb1,
                                                   const float* __restrict__ tw2,
                                                   const float* __restrict__ tb2,
                                                   float* __restrict__ temb,
                                                   ushortT* __restrict__ bufXT,
                                                   ushortT* __restrict__ xw1) {
    int bid = blockIdx.x;
    if (bid < nblkN) {
        int i = bid * 256 + threadIdx.x;
        if (i < n) { cnt[i] = 0; flag[i] = 0; }
        return;
    }
    if (bid < nblkN + csBlk) {
        size_t total = (size_t)n * CSR_CAP;
        size_t base = ((size_t)(bid - nblkN) * 256 + threadIdx.x) * 16;
        int4 sv = make_int4(n, n, n, n);
#pragma unroll
        for (int j = 0; j < 4; ++j) {
            size_t p = base + j * 4;
            if (p + 4 <= total) *(int4*)(cs + p) = sv;
            else for (size_t q = p; q < total; ++q) cs[q] = n;
        }
        return;
    }
    if (bid < nblkN + csBlk + 160) {
        int i = (bid - nblkN - csBlk) * 256 + threadIdx.x;
        if (i >= 40960) return;
        const float* src; int ST, M, base;
        if (i < 8192)       { src = w0; ST = 8; M = 128; base = 0; }
        else if (i < 16384) { src = w1; ST = 4; M = 64;  base = 8192; }
        else if (i < 24576) { src = w2; ST = 8; M = 128; base = 16384; }
        else                { src = w3; ST = 4; M = 64;  base = 24576; }
        int idx = i - base;
        int j = idx & 7;
        int lane = (idx >> 3) & 63;
        int rest = idx >> 9;
        int s = rest % ST;
        int kq = rest / ST;
        int k = kq * 32 + (lane >> 4) * 8 + j;
        int col = s * 16 + (lane & 15);
        wdst[i] = f2bf(src[(size_t)k * M + col]);
        return;
    }
    // temb block; threads 64-95/96-127 zero sentinel rows of bufXT / xw1
    __shared__ float emb[64], hid[64];
    int j = threadIdx.x;
    if (j >= 64 && j < 96)  ((unsigned int*)(bufXT + (size_t)n * 64))[j - 64] = 0u;
    if (j >= 96 && j < 128) ((unsigned int*)(xw1 + (size_t)n * 64))[j - 96] = 0u;
    if (j < 64) {
        float tf = (float)t[0];
        int h = j & 31;
        float freq = expf((float)h * -0.29710775393976190f);  // -ln(10000)/31
        float arg = tf * freq;
        emb[j] = (j < 32) ? sinf(arg) : cosf(arg);
    }
    __syncthreads();
    if (j < 64) {
        float a = tb1[j];
        for (int k = 0; k < 64; ++k) a = fmaf(emb[k], tw1[k * 64 + j], a);
        hid[j] = a / (1.0f + expf(-a));  // SiLU
    }
    __syncthreads();
    if (j < 64) {
        float o = tb2[j];
        for (int k = 0; k < 64; ++k) o = fmaf(hid[k], tw2[k * 64 + j], o);
        temb[j] = o;
    }
}

__global__ __launch_bounds__(256) void flags_kernel(const int* __restrict__ anm, int na,
                                                    const int* __restrict__ nrm, int nn,
                                                    int* __restrict__ flag) {
    int i = blockIdx.x * 256 + threadIdx.x;
    if (i < na) atomicMax(&flag[anm[i]], 1);
    if (i < nn) atomicMax(&flag[nrm[i]], 2);    // norm (2) overrides anm (1)
}

__global__ __launch_bounds__(256) void dinv_kernel(const int* __restrict__ cnt,
                                                   float* __restrict__ dinv, int n) {
    int i = blockIdx.x * 256 + threadIdx.x;
    if (i < n) dinv[i] = rsqrtf((float)cnt[i] + 1.0f);
}

// Padded-CSR fill, XCD-partitioned: block handles edge chunk (blockIdx>>3);
// only dst bucket == (blockIdx&7) written. CACHED edge reads (dst stream is
// L3-resident after the first of the 8 passes).
__global__ __launch_bounds__(256) void fill_csr_kernel(const int* __restrict__ ei,
                                                       int* __restrict__ cnt,
                                                       int* __restrict__ cs, int e, int bdiv) {
    int xcd = blockIdx.x & 7;
    int i = (blockIdx.x >> 3) * 256 + threadIdx.x;
    if (i >= e) return;
    int dst = ei[e + i];
    if (dst / bdiv != xcd) return;
    int src = ei[i];
    int p = atomicAdd(&cnt[dst], 1);
    if (p < CSR_CAP) cs[(size_t)dst * CSR_CAP + p] = src;
}

// ---- x_t = (noise_x + temb + label_emb[flag]) * dinv[row]  -> bf16 ----
__global__ __launch_bounds__(256) void xt_kernel(const float* __restrict__ nx,
                                                 const float* __restrict__ temb,
                                                 const float* __restrict__ lemb,
                                                 const int* __restrict__ flag,
                                                 const float* __restrict__ dinv,
                                                 ushortT* __restrict__ xt, int n) {
    int t = blockIdx.x * 256 + threadIdx.x;
    int total = n * 16;
    if (t >= total) return;
    int row = t >> 4;
    int c4 = (t & 15) * 4;
    float4 v = *(const float4*)(nx + (size_t)row * 64 + c4);
    float4 tv = *(const float4*)(temb + c4);
    v.x += tv.x; v.y += tv.y; v.z += tv.z; v.w += tv.w;
    int f = flag[row];
    if (f) {
        const float* le = lemb + (f == 1 ? 64 : 0);  // 1->label_emb[1], 2->label_emb[0]
        float4 lv = *(const float4*)(le + c4);
        v.x += lv.x; v.y += lv.y; v.z += lv.z; v.w += lv.w;
    }
    float dv = dinv[row];
    v.x *= dv; v.y *= dv; v.z *= dv; v.w *= dv;
    unsigned int p0 = (unsigned int)f2bf(v.x) | ((unsigned int)f2bf(v.y) << 16);
    unsigned int p1 = (unsigned int)f2bf(v.z) | ((unsigned int)f2bf(v.w) << 16);
    *(uint2*)(xt + (size_t)row * 64 + c4) = make_uint2(p0, p1);
}

// ---------------------------------------------------------------------------
// MFMA GEMM: Y[n][M] = A[n][K] @ W (bf16 in, f32 acc). Wave = 16 rows x M.
// ---------------------------------------------------------------------------
template <int KQT, int ST, bool BIAS_SILU, bool OUT_BF16, bool CAT, bool SCALE>
__global__ __launch_bounds__(256) void mfma_gemm_kernel(const ushortT* __restrict__ A1,
                                                        const ushortT* __restrict__ A2,
                                                        const ushortT* __restrict__ Wswz,
                                                        const float* __restrict__ bias,
                                                        const float* __restrict__ dinvp,
                                                        void* __restrict__ Yv, int n) {
    constexpr int M = ST * 16;
    constexpr int KA = (CAT ? (KQT / 2) : KQT) * 32;   // per-source row stride
    const int lane = threadIdx.x & 63;
    const int wid = threadIdx.x >> 6;
    const int row0 = blockIdx.x * 64 + wid * 16;
    const int arow = row0 + (lane & 15);
    const int kb = (lane >> 4) * 8;

    f32x4 acc[ST];
#pragma unroll
    for (int s = 0; s < ST; ++s) acc[s] = (f32x4){0.f, 0.f, 0.f, 0.f};

#pragma unroll
    for (int kq = 0; kq < KQT; ++kq) {
        const ushortT* Asrc = (CAT && kq >= KQT / 2) ? A2 : A1;
        const int kloc = (CAT && kq >= KQT / 2) ? (kq - KQT / 2) * 32 : kq * 32;
        short8v a = *(const short8v*)(Asrc + (size_t)arow * KA + kloc + kb);
        const ushortT* wp = Wswz + ((size_t)(kq * ST) * 64 + lane) * 8;
#pragma unroll
        for (int s = 0; s < ST; ++s) {
            short8v b = *(const short8v*)(wp + (size_t)s * 64 * 8);
            acc[s] = __builtin_amdgcn_mfma_f32_16x16x32_bf16(a, b, acc[s], 0, 0, 0);
        }
    }

    const int dcol = lane & 15;
    const int drow0 = row0 + (lane >> 4) * 4;
    float sc[4];
    if (SCALE) {
#pragma unroll
        for (int r = 0; r < 4; ++r) sc[r] = (drow0 + r < n) ? dinvp[drow0 + r] : 0.f;
    }
#pragma unroll
    for (int s = 0; s < ST; ++s) {
        float bv = BIAS_SILU ? bias[s * 16 + dcol] : 0.f;
#pragma unroll
        for (int r = 0; r < 4; ++r) {
            int row = drow0 + r;
            if (row >= n) continue;
            float v = acc[s][r];
            if (BIAS_SILU) { v += bv; v = v / (1.0f + expf(-v)); }
            if (SCALE) v *= sc[r];
            if (OUT_BF16) ((ushortT*)Yv)[(size_t)row * M + s * 16 + dcol] = f2bf(v);
            else          ((float*)Yv)[(size_t)row * M + s * 16 + dcol] = v;
        }
    }
}

// ---------------------------------------------------------------------------
// Sentinel-padded agg (R19): TWO nodes per wave, 32 unconditional gathers in
// flight, node index scalarized via readfirstlane. Overflow loop for deg>16.
// out[dst] = dinv[dst]*(sum_src xs[src] + xs[dst]) (+bias,silu,post-scale).
// ---------------------------------------------------------------------------
template <bool BIAS_SILU, bool OUT_BF16, bool POST_SCALE>
__global__ __launch_bounds__(256) void agg64_kernel(const ushortT* __restrict__ xw,
                                                    const int* __restrict__ cnt,
                                                    const int* __restrict__ cs,
                                                    const float* __restrict__ dinv,
                                                    const float* __restrict__ bias,
                                                    void* __restrict__ yv, int n) {
    int pair = (int)(((size_t)blockIdx.x * 256 + threadIdx.x) >> 6);
    int lane = threadIdx.x & 63;
    int nA = pair * 2;
    if (nA >= n) return;
    nA = __builtin_amdgcn_readfirstlane(nA);   // wave-uniform: force scalar
    int nB = nA + 1;
    bool hasB = (nB < n);
    const int* rA = cs + (size_t)nA * CSR_CAP;
    const int* rB = cs + (size_t)nB * CSR_CAP;

    int ia[16], ib[16];
#pragma unroll
    for (int j = 0; j < 16; ++j) ia[j] = rA[j];
#pragma unroll
    for (int j = 0; j < 16; ++j) ib[j] = hasB ? rB[j] : n;

    float va[16], vb[16];
#pragma unroll
    for (int j = 0; j < 16; ++j) va[j] = bf2f(xw[(size_t)ia[j] * 64 + lane]);
#pragma unroll
    for (int j = 0; j < 16; ++j) vb[j] = bf2f(xw[(size_t)ib[j] * 64 + lane]);

    float a0 = (va[0] + va[1]) + (va[2] + va[3]);
    float a1 = (va[4] + va[5]) + (va[6] + va[7]);
    float a2 = (va[8] + va[9]) + (va[10] + va[11]);
    float a3 = (va[12] + va[13]) + (va[14] + va[15]);
    float b0 = (vb[0] + vb[1]) + (vb[2] + vb[3]);
    float b1 = (vb[4] + vb[5]) + (vb[6] + vb[7]);
    float b2 = (vb[8] + vb[9]) + (vb[10] + vb[11]);
    float b3 = (vb[12] + vb[13]) + (vb[14] + vb[15]);

    // overflow (deg > 16), rare
    int cA = cnt[nA]; if (cA > CSR_CAP) cA = CSR_CAP;
    int cB = hasB ? cnt[nB] : 0; if (cB > CSR_CAP) cB = CSR_CAP;
    for (int j = 16; j < cA; ++j) a0 += bf2f(xw[(size_t)rA[j] * 64 + lane]);
    for (int j = 16; j < cB; ++j) b0 += bf2f(xw[(size_t)rB[j] * 64 + lane]);

    // epilogue A
    {
        float di = dinv[nA];
        float acc = (a0 + a1) + (a2 + a3);
        acc += bf2f(xw[(size_t)nA * 64 + lane]);   // self term (pre-scaled)
        acc *= di;
        if (BIAS_SILU) {
            acc += bias[lane];
            acc = acc / (1.0f + expf(-acc));
        }
        if (POST_SCALE) acc *= di;
        if (OUT_BF16) ((ushortT*)yv)[(size_t)nA * 64 + lane] = f2bf(acc);
        else          ((float*)yv)[(size_t)nA * 64 + lane] = acc;
    }
    // epilogue B
    if (hasB) {
        float di = dinv[nB];
        float acc = (b0 + b1) + (b2 + b3);
        acc += bf2f(xw[(size_t)nB * 64 + lane]);
        acc *= di;
        if (BIAS_SILU) {
            acc += bias[lane];
            acc = acc / (1.0f + expf(-acc));
        }
        if (POST_SCALE) acc *= di;
        if (OUT_BF16) ((ushortT*)yv)[(size_t)nB * 64 + lane] = f2bf(acc);
        else          ((float*)yv)[(size_t)nB * 64 + lane] = acc;
    }
}

extern "C" void kernel_launch(void* const* d_in, const int* in_sizes, int n_in,
                              void* d_out, int out_size, void* d_ws, size_t ws_size,
                              hipStream_t stream) {
    const float* noise_x = (const float*)d_in[0];
    const int*   edge    = (const int*)d_in[1];
    const int*   tptr    = (const int*)d_in[2];
    const int*   anm     = (const int*)d_in[3];
    const int*   nrm     = (const int*)d_in[4];
    const float* tw1     = (const float*)d_in[5];
    const float* tb1     = (const float*)d_in[6];
    const float* tw2     = (const float*)d_in[7];
    const float* tb2     = (const float*)d_in[8];
    const float* lemb    = (const float*)d_in[9];
    const float* w0      = (const float*)d_in[10];
    const float* b0      = (const float*)d_in[11];
    const float* w1      = (const float*)d_in[12];
    const float* b1      = (const float*)d_in[13];
    const float* w2      = (const float*)d_in[14];
    const float* b2      = (const float*)d_in[15];
    const float* w3      = (const float*)d_in[16];
    const float* b3      = (const float*)d_in[17];

    const int N = in_sizes[0] / 64;
    const int E = in_sizes[1] / 2;
    const int na = in_sizes[3];
    const int nn = in_sizes[4];
    float* out = (float*)d_out;

    // workspace carve-out (256B aligned)
    char* ws = (char*)d_ws;
    size_t o = 0;
    auto carve = [&](size_t bytes) -> char* {
        char* p = ws + o;
        o += (bytes + 255) & ~(size_t)255;
        return p;
    };
    int*     cnt      = (int*)carve((size_t)N * 4);
    int*     flag     = (int*)carve((size_t)N * 4);
    int*     cs       = (int*)carve((size_t)N * CSR_CAP * 4);
    float*   dinv     = (float*)carve((size_t)N * 4);
    float*   temb     = (float*)carve(256);
    ushortT* wswz     = (ushortT*)carve(40960 * 2);
    ushortT* bufXT    = (ushortT*)carve((size_t)(N + 1) * 64 * 2); // x_t*dinv -> h1s (+zero row N)
    ushortT* aggX     = (ushortT*)carve((size_t)N * 64 * 2);       // agg0 out
    ushortT* h0       = (ushortT*)carve((size_t)N * 128 * 2);      // G0 out (live to end)
    ushortT* xw1      = (ushortT*)carve((size_t)(N + 1) * 64 * 2); // G1 out -> z3 (+zero row N)
    ushortT* aggH1    = (ushortT*)carve((size_t)N * 64 * 2);       // agg2 out
    ushortT* h2       = (ushortT*)carve((size_t)N * 128 * 2);      // G2 out
    ushortT* h1s      = bufXT;                                      // reuse (row N stays zero)
    ushortT* z3       = xw1;                                        // reuse (row N stays zero)

    const int nblkN = (N + 255) / 256;
    const int nblkE = (E + 255) / 256;
    const int nmax = na > nn ? na : nn;
    const int aggBlk = (N + 7) / 8;          // 4 waves x 2 nodes per block
    const int gblk = (N + 63) / 64;          // 64 rows per mfma-gemm block
    const int bdiv = (N + 7) / 8;            // dst bucket size for XCD partition
    const int csBlk = (int)(((size_t)N * CSR_CAP + 4095) / 4096);  // 16 ints/thread

    prep_kernel<<<nblkN + csBlk + 161, 256, 0, stream>>>(cnt, flag, N, nblkN, csBlk, cs,
                                                         w0, w1, w2, w3, wswz,
                                                         tptr, tw1, tb1, tw2, tb2, temb,
                                                         bufXT, xw1);
    flags_kernel<<<(nmax + 255) / 256, 256, 0, stream>>>(anm, na, nrm, nn, flag);
    fill_csr_kernel<<<8 * nblkE, 256, 0, stream>>>(edge, cnt, cs, E, bdiv);
    dinv_kernel<<<nblkN, 256, 0, stream>>>(cnt, dinv, N);
    xt_kernel<<<((size_t)N * 16 + 255) / 256, 256, 0, stream>>>(noise_x, temb, lemb, flag, dinv, bufXT, N);

    // conv0: aggX = agg(x_t) [bf16]; h0 = silu(aggX @ w0 + b0) [bf16]
    agg64_kernel<false, true, false><<<aggBlk, 256, 0, stream>>>(bufXT, cnt, cs, dinv, nullptr, aggX, N);
    mfma_gemm_kernel<2, 8, true, true, false, false><<<gblk, 256, 0, stream>>>(aggX, nullptr, wswz, b0, nullptr, h0, N);
    // conv1: xw1 = (h0 @ w1)*dinv [bf16]; h1s = silu(agg+b1)*dinv [bf16]
    mfma_gemm_kernel<4, 4, false, true, false, true><<<gblk, 256, 0, stream>>>(h0, nullptr, wswz + 8192, nullptr, dinv, xw1, N);
    agg64_kernel<true, true, true><<<aggBlk, 256, 0, stream>>>(xw1, cnt, cs, dinv, b1, h1s, N);
    // conv2: aggH1 = agg(h1) [bf16]; h2 = silu(aggH1 @ w2 + b2) [bf16]
    agg64_kernel<false, true, false><<<aggBlk, 256, 0, stream>>>(h1s, cnt, cs, dinv, nullptr, aggH1, N);
    mfma_gemm_kernel<2, 8, true, true, false, false><<<gblk, 256, 0, stream>>>(aggH1, nullptr, wswz + 16384, b2, nullptr, h2, N);
    // conv3: z3 = (h2 @ w3a + h0 @ w3b)*dinv [bf16]; out = silu(agg + b3) [f32]
    mfma_gemm_kernel<8, 4, false, true, true, true><<<gblk, 256, 0, stream>>>(h2, h0, wswz + 24576, nullptr, dinv, z3, N);
    agg64_kernel<true, false, false><<<aggBlk, 256, 0, stream>>>(z3, cnt, cs, dinv, b3, out, N);
}

// Round 21
// 241.479 us; speedup vs baseline: 1.3311x; 1.0218x over previous
//
#include <hip/hip_runtime.h>
#include <math.h>

// ---------------------------------------------------------------------------
// GCN diffusion forward on MI355X — round 21.
// vs R20: SPLIT-LEVEL CSR.
//   primary cs[N][16]  — ONE 64B line per node (6.4MB; 800KB/XCD slice stays
//     L2-resident; ~10 temporally-clustered stores/line -> writeback ~once).
//   overflow cs2[N][32] — deg>16 only (~3% of nodes; sparse, tiny volume).
// agg reads 16 primary indices = one scalar-cache line; overflow loop uses
// cs2. Sentinel preset shrinks 19.2->6.4MB. Rest = R20.
// ---------------------------------------------------------------------------

typedef unsigned short ushortT;
typedef __attribute__((ext_vector_type(8))) short short8v;
typedef __attribute__((ext_vector_type(4))) float f32x4;

#define CAP1 16
#define CAP2 32
#define CAPT (CAP1 + CAP2)

__device__ __forceinline__ ushortT f2bf(float f) {
    unsigned int u = __float_as_uint(f);
    u += 0x7FFFu + ((u >> 16) & 1u);     // round-to-nearest-even
    return (ushortT)(u >> 16);
}
__device__ __forceinline__ float bf2f(ushortT u) {
    return __uint_as_float(((unsigned int)u) << 16);
}

// ---- merged prep ----
// blocks [0,nblkN): zero cnt/flag
// [nblkN, nblkN+csBlk): preset primary cs = sentinel N
// [.., +160): convw swizzle
// last: temb + zero gather-rows N of bufXT and xw1
__global__ __launch_bounds__(256) void prep_kernel(int* __restrict__ cnt,
                                                   int* __restrict__ flag,
                                                   int n, int nblkN, int csBlk,
                                                   int* __restrict__ cs,
                                                   const float* __restrict__ w0,
                                                   const float* __restrict__ w1,
                                                   const float* __restrict__ w2,
                                                   const float* __restrict__ w3,
                                                   ushortT* __restrict__ wdst,
                                                   const int* __restrict__ t,
                                                   const float* __restrict__ tw1,
                                                   const float* __restrict__ tb1,
                                                   const float* __restrict__ tw2,
                                                   const float* __restrict__ tb2,
                                                   float* __restrict__ temb,
                                                   ushortT* __restrict__ bufXT,
                                                   ushortT* __restrict__ xw1) {
    int bid = blockIdx.x;
    if (bid < nblkN) {
        int i = bid * 256 + threadIdx.x;
        if (i < n) { cnt[i] = 0; flag[i] = 0; }
        return;
    }
    if (bid < nblkN + csBlk) {
        size_t total = (size_t)n * CAP1;
        size_t base = ((size_t)(bid - nblkN) * 256 + threadIdx.x) * 16;
        int4 sv = make_int4(n, n, n, n);
#pragma unroll
        for (int j = 0; j < 4; ++j) {
            size_t p = base + j * 4;
            if (p + 4 <= total) *(int4*)(cs + p) = sv;
            else for (size_t q = p; q < total; ++q) cs[q] = n;
        }
        return;
    }
    if (bid < nblkN + csBlk + 160) {
        int i = (bid - nblkN - csBlk) * 256 + threadIdx.x;
        if (i >= 40960) return;
        const float* src; int ST, M, base;
        if (i < 8192)       { src = w0; ST = 8; M = 128; base = 0; }
        else if (i < 16384) { src = w1; ST = 4; M = 64;  base = 8192; }
        else if (i < 24576) { src = w2; ST = 8; M = 128; base = 16384; }
        else                { src = w3; ST = 4; M = 64;  base = 24576; }
        int idx = i - base;
        int j = idx & 7;
        int lane = (idx >> 3) & 63;
        int rest = idx >> 9;
        int s = rest % ST;
        int kq = rest / ST;
        int k = kq * 32 + (lane >> 4) * 8 + j;
        int col = s * 16 + (lane & 15);
        wdst[i] = f2bf(src[(size_t)k * M + col]);
        return;
    }
    // temb block; threads 64-95/96-127 zero sentinel rows of bufXT / xw1
    __shared__ float emb[64], hid[64];
    int j = threadIdx.x;
    if (j >= 64 && j < 96)  ((unsigned int*)(bufXT + (size_t)n * 64))[j - 64] = 0u;
    if (j >= 96 && j < 128) ((unsigned int*)(xw1 + (size_t)n * 64))[j - 96] = 0u;
    if (j < 64) {
        float tf = (float)t[0];
        int h = j & 31;
        float freq = expf((float)h * -0.29710775393976190f);  // -ln(10000)/31
        float arg = tf * freq;
        emb[j] = (j < 32) ? sinf(arg) : cosf(arg);
    }
    __syncthreads();
    if (j < 64) {
        float a = tb1[j];
        for (int k = 0; k < 64; ++k) a = fmaf(emb[k], tw1[k * 64 + j], a);
        hid[j] = a / (1.0f + expf(-a));  // SiLU
    }
    __syncthreads();
    if (j < 64) {
        float o = tb2[j];
        for (int k = 0; k < 64; ++k) o = fmaf(hid[k], tw2[k * 64 + j], o);
        temb[j] = o;
    }
}

__global__ __launch_bounds__(256) void flags_kernel(const int* __restrict__ anm, int na,
                                                    const int* __restrict__ nrm, int nn,
                                                    int* __restrict__ flag) {
    int i = blockIdx.x * 256 + threadIdx.x;
    if (i < na) atomicMax(&flag[anm[i]], 1);
    if (i < nn) atomicMax(&flag[nrm[i]], 2);    // norm (2) overrides anm (1)
}

__global__ __launch_bounds__(256) void dinv_kernel(const int* __restrict__ cnt,
                                                   float* __restrict__ dinv, int n) {
    int i = blockIdx.x * 256 + threadIdx.x;
    if (i < n) dinv[i] = rsqrtf((float)cnt[i] + 1.0f);
}

// Split-CSR fill, XCD-partitioned: block handles edge chunk (blockIdx>>3);
// only dst bucket == (blockIdx&7) written. Cached edge reads.
// p<16 -> primary cs (1 line/node); 16<=p<48 -> overflow cs2.
__global__ __launch_bounds__(256) void fill_csr_kernel(const int* __restrict__ ei,
                                                       int* __restrict__ cnt,
                                                       int* __restrict__ cs,
                                                       int* __restrict__ cs2,
                                                       int e, int bdiv) {
    int xcd = blockIdx.x & 7;
    int i = (blockIdx.x >> 3) * 256 + threadIdx.x;
    if (i >= e) return;
    int dst = ei[e + i];
    if (dst / bdiv != xcd) return;
    int src = ei[i];
    int p = atomicAdd(&cnt[dst], 1);
    if (p < CAP1)      cs[(size_t)dst * CAP1 + p] = src;
    else if (p < CAPT) cs2[(size_t)dst * CAP2 + (p - CAP1)] = src;
}

// ---- x_t = (noise_x + temb + label_emb[flag]) * dinv[row]  -> bf16 ----
__global__ __launch_bounds__(256) void xt_kernel(const float* __restrict__ nx,
                                                 const float* __restrict__ temb,
                                                 const float* __restrict__ lemb,
                                                 const int* __restrict__ flag,
                                                 const float* __restrict__ dinv,
                                                 ushortT* __restrict__ xt, int n) {
    int t = blockIdx.x * 256 + threadIdx.x;
    int total = n * 16;
    if (t >= total) return;
    int row = t >> 4;
    int c4 = (t & 15) * 4;
    float4 v = *(const float4*)(nx + (size_t)row * 64 + c4);
    float4 tv = *(const float4*)(temb + c4);
    v.x += tv.x; v.y += tv.y; v.z += tv.z; v.w += tv.w;
    int f = flag[row];
    if (f) {
        const float* le = lemb + (f == 1 ? 64 : 0);  // 1->label_emb[1], 2->label_emb[0]
        float4 lv = *(const float4*)(le + c4);
        v.x += lv.x; v.y += lv.y; v.z += lv.z; v.w += lv.w;
    }
    float dv = dinv[row];
    v.x *= dv; v.y *= dv; v.z *= dv; v.w *= dv;
    unsigned int p0 = (unsigned int)f2bf(v.x) | ((unsigned int)f2bf(v.y) << 16);
    unsigned int p1 = (unsigned int)f2bf(v.z) | ((unsigned int)f2bf(v.w) << 16);
    *(uint2*)(xt + (size_t)row * 64 + c4) = make_uint2(p0, p1);
}

// ---------------------------------------------------------------------------
// MFMA GEMM: Y[n][M] = A[n][K] @ W (bf16 in, f32 acc). Wave = 16 rows x M.
// ---------------------------------------------------------------------------
template <int KQT, int ST, bool BIAS_SILU, bool OUT_BF16, bool CAT, bool SCALE>
__global__ __launch_bounds__(256) void mfma_gemm_kernel(const ushortT* __restrict__ A1,
                                                        const ushortT* __restrict__ A2,
                                                        const ushortT* __restrict__ Wswz,
                                                        const float* __restrict__ bias,
                                                        const float* __restrict__ dinvp,
                                                        void* __restrict__ Yv, int n) {
    constexpr int M = ST * 16;
    constexpr int KA = (CAT ? (KQT / 2) : KQT) * 32;   // per-source row stride
    const int lane = threadIdx.x & 63;
    const int wid = threadIdx.x >> 6;
    const int row0 = blockIdx.x * 64 + wid * 16;
    const int arow = row0 + (lane & 15);
    const int kb = (lane >> 4) * 8;

    f32x4 acc[ST];
#pragma unroll
    for (int s = 0; s < ST; ++s) acc[s] = (f32x4){0.f, 0.f, 0.f, 0.f};

#pragma unroll
    for (int kq = 0; kq < KQT; ++kq) {
        const ushortT* Asrc = (CAT && kq >= KQT / 2) ? A2 : A1;
        const int kloc = (CAT && kq >= KQT / 2) ? (kq - KQT / 2) * 32 : kq * 32;
        short8v a = *(const short8v*)(Asrc + (size_t)arow * KA + kloc + kb);
        const ushortT* wp = Wswz + ((size_t)(kq * ST) * 64 + lane) * 8;
#pragma unroll
        for (int s = 0; s < ST; ++s) {
            short8v b = *(const short8v*)(wp + (size_t)s * 64 * 8);
            acc[s] = __builtin_amdgcn_mfma_f32_16x16x32_bf16(a, b, acc[s], 0, 0, 0);
        }
    }

    const int dcol = lane & 15;
    const int drow0 = row0 + (lane >> 4) * 4;
    float sc[4];
    if (SCALE) {
#pragma unroll
        for (int r = 0; r < 4; ++r) sc[r] = (drow0 + r < n) ? dinvp[drow0 + r] : 0.f;
    }
#pragma unroll
    for (int s = 0; s < ST; ++s) {
        float bv = BIAS_SILU ? bias[s * 16 + dcol] : 0.f;
#pragma unroll
        for (int r = 0; r < 4; ++r) {
            int row = drow0 + r;
            if (row >= n) continue;
            float v = acc[s][r];
            if (BIAS_SILU) { v += bv; v = v / (1.0f + expf(-v)); }
            if (SCALE) v *= sc[r];
            if (OUT_BF16) ((ushortT*)Yv)[(size_t)row * M + s * 16 + dcol] = f2bf(v);
            else          ((float*)Yv)[(size_t)row * M + s * 16 + dcol] = v;
        }
    }
}

// ---------------------------------------------------------------------------
// Sentinel-padded split-CSR agg: TWO nodes per wave, 32 unconditional gathers
// in flight; node index scalarized (readfirstlane); primary indices = one
// 64B scalar-cache line per node. Overflow (deg>16) from cs2.
// out[dst] = dinv[dst]*(sum_src xs[src] + xs[dst]) (+bias,silu,post-scale).
// ---------------------------------------------------------------------------
template <bool BIAS_SILU, bool OUT_BF16, bool POST_SCALE>
__global__ __launch_bounds__(256) void agg64_kernel(const ushortT* __restrict__ xw,
                                                    const int* __restrict__ cnt,
                                                    const int* __restrict__ cs,
                                                    const int* __restrict__ cs2,
                                                    const float* __restrict__ dinv,
                                                    const float* __restrict__ bias,
                                                    void* __restrict__ yv, int n) {
    int pair = (int)(((size_t)blockIdx.x * 256 + threadIdx.x) >> 6);
    int lane = threadIdx.x & 63;
    int nA = pair * 2;
    if (nA >= n) return;
    nA = __builtin_amdgcn_readfirstlane(nA);   // wave-uniform: force scalar
    int nB = nA + 1;
    bool hasB = (nB < n);
    const int* rA = cs + (size_t)nA * CAP1;
    const int* rB = cs + (size_t)nB * CAP1;

    int ia[16], ib[16];
#pragma unroll
    for (int j = 0; j < 16; ++j) ia[j] = rA[j];
#pragma unroll
    for (int j = 0; j < 16; ++j) ib[j] = hasB ? rB[j] : n;

    float va[16], vb[16];
#pragma unroll
    for (int j = 0; j < 16; ++j) va[j] = bf2f(xw[(size_t)ia[j] * 64 + lane]);
#pragma unroll
    for (int j = 0; j < 16; ++j) vb[j] = bf2f(xw[(size_t)ib[j] * 64 + lane]);

    float a0 = (va[0] + va[1]) + (va[2] + va[3]);
    float a1 = (va[4] + va[5]) + (va[6] + va[7]);
    float a2 = (va[8] + va[9]) + (va[10] + va[11]);
    float a3 = (va[12] + va[13]) + (va[14] + va[15]);
    float b0 = (vb[0] + vb[1]) + (vb[2] + vb[3]);
    float b1 = (vb[4] + vb[5]) + (vb[6] + vb[7]);
    float b2 = (vb[8] + vb[9]) + (vb[10] + vb[11]);
    float b3 = (vb[12] + vb[13]) + (vb[14] + vb[15]);

    // overflow (deg > 16) from cs2, rare
    int cA = cnt[nA]; if (cA > CAPT) cA = CAPT;
    int cB = hasB ? cnt[nB] : 0; if (cB > CAPT) cB = CAPT;
    for (int j = CAP1; j < cA; ++j)
        a0 += bf2f(xw[(size_t)cs2[(size_t)nA * CAP2 + (j - CAP1)] * 64 + lane]);
    for (int j = CAP1; j < cB; ++j)
        b0 += bf2f(xw[(size_t)cs2[(size_t)nB * CAP2 + (j - CAP1)] * 64 + lane]);

    // epilogue A
    {
        float di = dinv[nA];
        float acc = (a0 + a1) + (a2 + a3);
        acc += bf2f(xw[(size_t)nA * 64 + lane]);   // self term (pre-scaled)
        acc *= di;
        if (BIAS_SILU) {
            acc += bias[lane];
            acc = acc / (1.0f + expf(-acc));
        }
        if (POST_SCALE) acc *= di;
        if (OUT_BF16) ((ushortT*)yv)[(size_t)nA * 64 + lane] = f2bf(acc);
        else          ((float*)yv)[(size_t)nA * 64 + lane] = acc;
    }
    // epilogue B
    if (hasB) {
        float di = dinv[nB];
        float acc = (b0 + b1) + (b2 + b3);
        acc += bf2f(xw[(size_t)nB * 64 + lane]);
        acc *= di;
        if (BIAS_SILU) {
            acc += bias[lane];
            acc = acc / (1.0f + expf(-acc));
        }
        if (POST_SCALE) acc *= di;
        if (OUT_BF16) ((ushortT*)yv)[(size_t)nB * 64 + lane] = f2bf(acc);
        else          ((float*)yv)[(size_t)nB * 64 + lane] = acc;
    }
}

extern "C" void kernel_launch(void* const* d_in, const int* in_sizes, int n_in,
                              void* d_out, int out_size, void* d_ws, size_t ws_size,
                              hipStream_t stream) {
    const float* noise_x = (const float*)d_in[0];
    const int*   edge    = (const int*)d_in[1];
    const int*   tptr    = (const int*)d_in[2];
    const int*   anm     = (const int*)d_in[3];
    const int*   nrm     = (const int*)d_in[4];
    const float* tw1     = (const float*)d_in[5];
    const float* tb1     = (const float*)d_in[6];
    const float* tw2     = (const float*)d_in[7];
    const float* tb2     = (const float*)d_in[8];
    const float* lemb    = (const float*)d_in[9];
    const float* w0      = (const float*)d_in[10];
    const float* b0      = (const float*)d_in[11];
    const float* w1      = (const float*)d_in[12];
    const float* b1      = (const float*)d_in[13];
    const float* w2      = (const float*)d_in[14];
    const float* b2      = (const float*)d_in[15];
    const float* w3      = (const float*)d_in[16];
    const float* b3      = (const float*)d_in[17];

    const int N = in_sizes[0] / 64;
    const int E = in_sizes[1] / 2;
    const int na = in_sizes[3];
    const int nn = in_sizes[4];
    float* out = (float*)d_out;

    // workspace carve-out (256B aligned)
    char* ws = (char*)d_ws;
    size_t o = 0;
    auto carve = [&](size_t bytes) -> char* {
        char* p = ws + o;
        o += (bytes + 255) & ~(size_t)255;
        return p;
    };
    int*     cnt      = (int*)carve((size_t)N * 4);
    int*     flag     = (int*)carve((size_t)N * 4);
    int*     cs       = (int*)carve((size_t)N * CAP1 * 4);
    int*     cs2      = (int*)carve((size_t)N * CAP2 * 4);
    float*   dinv     = (float*)carve((size_t)N * 4);
    float*   temb     = (float*)carve(256);
    ushortT* wswz     = (ushortT*)carve(40960 * 2);
    ushortT* bufXT    = (ushortT*)carve((size_t)(N + 1) * 64 * 2); // x_t*dinv -> h1s (+zero row N)
    ushortT* aggX     = (ushortT*)carve((size_t)N * 64 * 2);       // agg0 out
    ushortT* h0       = (ushortT*)carve((size_t)N * 128 * 2);      // G0 out (live to end)
    ushortT* xw1      = (ushortT*)carve((size_t)(N + 1) * 64 * 2); // G1 out -> z3 (+zero row N)
    ushortT* aggH1    = (ushortT*)carve((size_t)N * 64 * 2);       // agg2 out
    ushortT* h2       = (ushortT*)carve((size_t)N * 128 * 2);      // G2 out
    ushortT* h1s      = bufXT;                                      // reuse (row N stays zero)
    ushortT* z3       = xw1;                                        // reuse (row N stays zero)

    const int nblkN = (N + 255) / 256;
    const int nblkE = (E + 255) / 256;
    const int nmax = na > nn ? na : nn;
    const int aggBlk = (N + 7) / 8;          // 4 waves x 2 nodes per block
    const int gblk = (N + 63) / 64;          // 64 rows per mfma-gemm block
    const int bdiv = (N + 7) / 8;            // dst bucket size for XCD partition
    const int csBlk = (int)(((size_t)N * CAP1 + 4095) / 4096);     // 16 ints/thread

    prep_kernel<<<nblkN + csBlk + 161, 256, 0, stream>>>(cnt, flag, N, nblkN, csBlk, cs,
                                                         w0, w1, w2, w3, wswz,
                                                         tptr, tw1, tb1, tw2, tb2, temb,
                                                         bufXT, xw1);
    flags_kernel<<<(nmax + 255) / 256, 256, 0, stream>>>(anm, na, nrm, nn, flag);
    fill_csr_kernel<<<8 * nblkE, 256, 0, stream>>>(edge, cnt, cs, cs2, E, bdiv);
    dinv_kernel<<<nblkN, 256, 0, stream>>>(cnt, dinv, N);
    xt_kernel<<<((size_t)N * 16 + 255) / 256, 256, 0, stream>>>(noise_x, temb, lemb, flag, dinv, bufXT, N);

    // conv0: aggX = agg(x_t) [bf16]; h0 = silu(aggX @ w0 + b0) [bf16]
    agg64_kernel<false, true, false><<<aggBlk, 256, 0, stream>>>(bufXT, cnt, cs, cs2, dinv, nullptr, aggX, N);
    mfma_gemm_kernel<2, 8, true, true, false, false><<<gblk, 256, 0, stream>>>(aggX, nullptr, wswz, b0, nullptr, h0, N);
    // conv1: xw1 = (h0 @ w1)*dinv [bf16]; h1s = silu(agg+b1)*dinv [bf16]
    mfma_gemm_kernel<4, 4, false, true, false, true><<<gblk, 256, 0, stream>>>(h0, nullptr, wswz + 8192, nullptr, dinv, xw1, N);
    agg64_kernel<true, true, true><<<aggBlk, 256, 0, stream>>>(xw1, cnt, cs, cs2, dinv, b1, h1s, N);
    // conv2: aggH1 = agg(h1) [bf16]; h2 = silu(aggH1 @ w2 + b2) [bf16]
    agg64_kernel<false, true, false><<<aggBlk, 256, 0, stream>>>(h1s, cnt, cs, cs2, dinv, nullptr, aggH1, N);
    mfma_gemm_kernel<2, 8, true, true, false, false><<<gblk, 256, 0, stream>>>(aggH1, nullptr, wswz + 16384, b2, nullptr, h2, N);
    // conv3: z3 = (h2 @ w3a + h0 @ w3b)*dinv [bf16]; out = silu(agg + b3) [f32]
    mfma_gemm_kernel<8, 4, false, true, true, true><<<gblk, 256, 0, stream>>>(h2, h0, wswz + 24576, nullptr, dinv, z3, N);
    agg64_kernel<true, false, false><<<aggBlk, 256, 0, stream>>>(z3, cnt, cs, cs2, dinv, b3, out, N);
}